// Round 9
// baseline (520.487 us; speedup 1.0000x reference)
//
#include <hip/hip_runtime.h>
#include <hip/hip_bf16.h>
#include <hip/hip_fp16.h>
#include <math.h>

#define NUM_USERS 100000
#define NUM_ITEMS 50000
#define N_NODES   150000
#define DIM       64
#define VAL_SCALE 16383.0f
#define VAL_INV   (1.0f / 16383.0f)

// scatter bucketing: 512 rows per bucket, fixed-capacity regions.
// ALL pk8 claims are 8-slot (64B) aligned -> no partial-line write
// amplification (r5/r6 lesson). CAP=12 -> 22.3KB LDS -> 6 WGs/CU.
// SLOTS=36864 gives hard headroom: entries(+6sig 22.6K) + drain waste
// (<=1536x7=10.8K) + overflow pads (~1K) < 36864 (r8 lesson: 1792 WGs
// at SLOTS=32768 could overrun the bucket region).
#define SSHIFT 9
#define SROWS  512
#define NBS    ((N_NODES + SROWS - 1) / SROWS)   // 293
#define CAP    12          // LDS buffer entries per bucket
#define FLUSH  8           // flush granularity (64B line of uint2)
#define SCAT_WGS 1536      // 6 WGs/CU x 256 CUs (22.3 KB LDS each)
#define GPAD   16          // pad global cursors to 64B lines
#define SLOTS  36864       // pk8 slots per bucket (x8 aligned)
#define PKSLOTS 22744      // final pk slots per bucket (mean + 6 sigma, x8 aligned)
#define SENTINEL 0xFFFFFFFFu
#define BBT 512            // bucket_build threads per WG (1:1 with SROWS)

// ---------------------------------------------------------------------------
// cur = fp16(concat(emb_user, emb_item)). total4 = N_NODES*16 (4 elems/thread)
__global__ void copy_init_kernel(const float4* __restrict__ eu, const float4* __restrict__ ei,
                                 ushort4* __restrict__ cur, int total4) {
    int i = blockIdx.x * blockDim.x + threadIdx.x;
    if (i >= total4) return;
    const int user_lim = NUM_USERS * (DIM / 4);
    float4 v = (i < user_lim) ? eu[i] : ei[i - user_lim];
    ushort4 h;
    h.x = __half_as_ushort(__float2half_rn(v.x));
    h.y = __half_as_ushort(__float2half_rn(v.y));
    h.z = __half_as_ushort(__float2half_rn(v.z));
    h.w = __half_as_ushort(__float2half_rn(v.w));
    cur[i] = h;
}

// ---------------------------------------------------------------------------
__global__ void gcur_init_kernel(int* __restrict__ gcur) {
    int b = blockIdx.x * blockDim.x + threadIdx.x;
    if (b < NBS) gcur[b * GPAD] = b * SLOTS;
}

// ---------------------------------------------------------------------------
// LDS-binned aggregated scatter: 2-edge vectorized input loads (int2/float2),
// uint4 16B line-flush stores, 8-slot (64B) aligned claims everywhere.
// NO per-edge global atomics (r6 lesson). 6 WGs/CU for latency hiding.
__global__ __launch_bounds__(256) void binned_scatter_kernel(
        const int* __restrict__ rows, const int* __restrict__ cols,
        const float* __restrict__ vals, int* __restrict__ gcur,
        uint2* __restrict__ pk8, int nnz) {
    __shared__ unsigned       lbufA[NBS * CAP];   // col | val<<18   (14.1 KB)
    __shared__ unsigned short lbufB[NBS * CAP];   // row-in-bucket    (7.0 KB)
    __shared__ int            lcur[NBS];          //                  (1.2 KB)
    int t = threadIdx.x;
    for (int i = t; i < NBS; i += 256) lcur[i] = 0;
    __syncthreads();

    int per_wg = (((nnz + (int)gridDim.x - 1) / (int)gridDim.x) + 1) & ~1;  // even
    int e0 = blockIdx.x * per_wg;
    int e1 = min(e0 + per_wg, nnz);

    #define PROC(rr, cc, vv) { \
        int r = (rr); \
        unsigned q = __float2uint_rn((vv) * VAL_SCALE); \
        unsigned ax = (unsigned)(cc) | (q << 18); \
        int b = r >> SSHIFT; \
        int pos = atomicAdd(&lcur[b], 1); \
        if (pos < CAP) { \
            lbufA[b * CAP + pos] = ax; \
            lbufB[b * CAP + pos] = (unsigned short)(r - (b << SSHIFT)); \
        } else { \
            atomicSub(&lcur[b], 1); \
            int p = atomicAdd(&gcur[b * GPAD], 8); \
            *(uint4*)(&pk8[p])     = make_uint4(ax, (unsigned)r, 0u, SENTINEL); \
            *(uint4*)(&pk8[p + 2]) = make_uint4(0u, SENTINEL, 0u, SENTINEL); \
            *(uint4*)(&pk8[p + 4]) = make_uint4(0u, SENTINEL, 0u, SENTINEL); \
            *(uint4*)(&pk8[p + 6]) = make_uint4(0u, SENTINEL, 0u, SENTINEL); \
        } }

    for (int base = e0; base < e1; base += 512) {
        int e = base + t * 2;
        if (e + 1 < e1) {
            int2   r2 = *(const int2*)(rows + e);
            int2   c2 = *(const int2*)(cols + e);
            float2 v2 = *(const float2*)(vals + e);
            PROC(r2.x, c2.x, v2.x)
            PROC(r2.y, c2.y, v2.y)
        } else if (e < e1) {
            PROC(rows[e], cols[e], vals[e])
        }
        __syncthreads();
        // flush all full 8-entry groups: one thread writes each 64B line (4x uint4)
        for (int b2 = t; b2 < NBS; b2 += 256) {
            int c = lcur[b2];
            if (c >= FLUSH) {
                int ng = c >> 3;
                int p = atomicAdd(&gcur[b2 * GPAD], ng * 8);
                unsigned rbase = (unsigned)(b2 << SSHIFT);
                for (int j = 0; j < ng * 8; j += 2) {
                    uint4 q = make_uint4(lbufA[b2 * CAP + j],     rbase + lbufB[b2 * CAP + j],
                                         lbufA[b2 * CAP + j + 1], rbase + lbufB[b2 * CAP + j + 1]);
                    *(uint4*)(&pk8[p + j]) = q;
                }
                int rem = c - ng * 8;
                for (int j = 0; j < rem; ++j) {
                    lbufA[b2 * CAP + j] = lbufA[b2 * CAP + ng * 8 + j];
                    lbufB[b2 * CAP + j] = lbufB[b2 * CAP + ng * 8 + j];
                }
                lcur[b2] = rem;
            }
        }
        __syncthreads();
    }
    // drain remainders (c <= 7): claim a full aligned line, pad with sentinels
    for (int b2 = t; b2 < NBS; b2 += 256) {
        int c = lcur[b2];
        if (c > 0) {
            int p = atomicAdd(&gcur[b2 * GPAD], 8);
            unsigned rbase = (unsigned)(b2 << SSHIFT);
            for (int j = 0; j < 8; j += 2) {
                unsigned a0 = (j     < c) ? lbufA[b2 * CAP + j]             : 0u;
                unsigned b0 = (j     < c) ? rbase + lbufB[b2 * CAP + j]     : SENTINEL;
                unsigned a1 = (j + 1 < c) ? lbufA[b2 * CAP + j + 1]         : 0u;
                unsigned b1 = (j + 1 < c) ? rbase + lbufB[b2 * CAP + j + 1] : SENTINEL;
                *(uint4*)(&pk8[p + j]) = make_uint4(a0, b0, a1, b1);
            }
        }
    }
}

// ---------------------------------------------------------------------------
// fused count + scan + CSR: 512 threads, uint4 paired-entry loads, 4-deep
// load pipeline, LDS atomics only. Two sequential reads of the bucket's pk8
// segment; fixed per-bucket pk bases (b*PKSLOTS).
__global__ __launch_bounds__(BBT) void bucket_build_kernel(const int* __restrict__ gcur,
                                                           const uint2* __restrict__ pk8,
                                                           unsigned* __restrict__ pk,
                                                           int* __restrict__ rowbeg,
                                                           int* __restrict__ rowend) {
    __shared__ int lc[SROWS];    // counts, then cursors
    __shared__ int ps[SROWS];    // scan
    int b  = blockIdx.x;
    int r0 = b * SROWS;
    int nr = min(r0 + SROWS, N_NODES) - r0;
    int t  = threadIdx.x;        // 0..511, maps 1:1 to SROWS
    lc[t] = 0;
    __syncthreads();

    const uint4* p4 = (const uint4*)pk8;      // 2 entries per load
    int i0   = (b * SLOTS) >> 1;              // claims all 8-aligned -> pair-aligned
    int iend = gcur[b * GPAD] >> 1;

    #define CNT(q) { \
        if ((q).y != SENTINEL) atomicAdd(&lc[(int)(q).y - r0], 1); \
        if ((q).w != SENTINEL) atomicAdd(&lc[(int)(q).w - r0], 1); }

    int i = i0 + t;
    for (; i + 3 * BBT < iend; i += 4 * BBT) {
        uint4 qa = p4[i], qb = p4[i + BBT], qc = p4[i + 2 * BBT], qd = p4[i + 3 * BBT];
        CNT(qa) CNT(qb) CNT(qc) CNT(qd)
    }
    for (; i < iend; i += BBT) { uint4 qa = p4[i]; CNT(qa) }
    __syncthreads();

    int c = lc[t];
    ps[t] = c;
    __syncthreads();
    #pragma unroll
    for (int off = 1; off < SROWS; off <<= 1) {
        int u = (t >= off) ? ps[t - off] : 0;
        __syncthreads();
        ps[t] += u;
        __syncthreads();
    }
    int base = b * PKSLOTS + ps[t] - c;   // exclusive prefix
    if (t < nr) { rowbeg[r0 + t] = base; rowend[r0 + t] = base + c; }
    lc[t] = base;                          // cursor
    __syncthreads();

    #define PLC(q) { \
        if ((q).y != SENTINEL) { int p_ = atomicAdd(&lc[(int)(q).y - r0], 1); pk[p_] = (q).x; } \
        if ((q).w != SENTINEL) { int p_ = atomicAdd(&lc[(int)(q).w - r0], 1); pk[p_] = (q).z; } }

    i = i0 + t;
    for (; i + 3 * BBT < iend; i += 4 * BBT) {
        uint4 qa = p4[i], qb = p4[i + BBT], qc = p4[i + 2 * BBT], qd = p4[i + 3 * BBT];
        PLC(qa) PLC(qb) PLC(qc) PLC(qd)
    }
    for (; i < iend; i += BBT) { uint4 qa = p4[i]; PLC(qa) }
}

// ---------------------------------------------------------------------------
// edge-stream row reduction (v1 layout, proven fastest): wave-uniform row,
// lane = dim. pk[e] loads scalarize (row uniform); each edge is one 128B-
// contiguous wave gather. 16-deep unroll for latency hiding.
__device__ __forceinline__ float row_pull(const int* __restrict__ rowbeg,
                                          const int* __restrict__ rowend,
                                          const unsigned* __restrict__ pk,
                                          const __half* __restrict__ x,
                                          int row, int lane) {
    int s0 = rowbeg[row];
    int s1 = rowend[row];
    float acc = 0.f;
    int e = s0;
    for (; e + 16 <= s1; e += 16) {
        unsigned p0 = pk[e + 0],  p1 = pk[e + 1],  p2 = pk[e + 2],  p3 = pk[e + 3];
        unsigned p4 = pk[e + 4],  p5 = pk[e + 5],  p6 = pk[e + 6],  p7 = pk[e + 7];
        unsigned p8 = pk[e + 8],  p9 = pk[e + 9],  pA = pk[e + 10], pB = pk[e + 11];
        unsigned pC = pk[e + 12], pD = pk[e + 13], pE = pk[e + 14], pF = pk[e + 15];
        float x0 = __half2float(x[((p0 & 0x3FFFFu) << 6) + lane]);
        float x1 = __half2float(x[((p1 & 0x3FFFFu) << 6) + lane]);
        float x2 = __half2float(x[((p2 & 0x3FFFFu) << 6) + lane]);
        float x3 = __half2float(x[((p3 & 0x3FFFFu) << 6) + lane]);
        float x4 = __half2float(x[((p4 & 0x3FFFFu) << 6) + lane]);
        float x5 = __half2float(x[((p5 & 0x3FFFFu) << 6) + lane]);
        float x6 = __half2float(x[((p6 & 0x3FFFFu) << 6) + lane]);
        float x7 = __half2float(x[((p7 & 0x3FFFFu) << 6) + lane]);
        float x8 = __half2float(x[((p8 & 0x3FFFFu) << 6) + lane]);
        float x9 = __half2float(x[((p9 & 0x3FFFFu) << 6) + lane]);
        float xA = __half2float(x[((pA & 0x3FFFFu) << 6) + lane]);
        float xB = __half2float(x[((pB & 0x3FFFFu) << 6) + lane]);
        float xC = __half2float(x[((pC & 0x3FFFFu) << 6) + lane]);
        float xD = __half2float(x[((pD & 0x3FFFFu) << 6) + lane]);
        float xE = __half2float(x[((pE & 0x3FFFFu) << 6) + lane]);
        float xF = __half2float(x[((pF & 0x3FFFFu) << 6) + lane]);
        acc = fmaf((float)(p0 >> 18), x0, acc);
        acc = fmaf((float)(p1 >> 18), x1, acc);
        acc = fmaf((float)(p2 >> 18), x2, acc);
        acc = fmaf((float)(p3 >> 18), x3, acc);
        acc = fmaf((float)(p4 >> 18), x4, acc);
        acc = fmaf((float)(p5 >> 18), x5, acc);
        acc = fmaf((float)(p6 >> 18), x6, acc);
        acc = fmaf((float)(p7 >> 18), x7, acc);
        acc = fmaf((float)(p8 >> 18), x8, acc);
        acc = fmaf((float)(p9 >> 18), x9, acc);
        acc = fmaf((float)(pA >> 18), xA, acc);
        acc = fmaf((float)(pB >> 18), xB, acc);
        acc = fmaf((float)(pC >> 18), xC, acc);
        acc = fmaf((float)(pD >> 18), xD, acc);
        acc = fmaf((float)(pE >> 18), xE, acc);
        acc = fmaf((float)(pF >> 18), xF, acc);
    }
    for (; e + 8 <= s1; e += 8) {
        unsigned p0 = pk[e + 0], p1 = pk[e + 1], p2 = pk[e + 2], p3 = pk[e + 3];
        unsigned p4 = pk[e + 4], p5 = pk[e + 5], p6 = pk[e + 6], p7 = pk[e + 7];
        float x0 = __half2float(x[((p0 & 0x3FFFFu) << 6) + lane]);
        float x1 = __half2float(x[((p1 & 0x3FFFFu) << 6) + lane]);
        float x2 = __half2float(x[((p2 & 0x3FFFFu) << 6) + lane]);
        float x3 = __half2float(x[((p3 & 0x3FFFFu) << 6) + lane]);
        float x4 = __half2float(x[((p4 & 0x3FFFFu) << 6) + lane]);
        float x5 = __half2float(x[((p5 & 0x3FFFFu) << 6) + lane]);
        float x6 = __half2float(x[((p6 & 0x3FFFFu) << 6) + lane]);
        float x7 = __half2float(x[((p7 & 0x3FFFFu) << 6) + lane]);
        acc = fmaf((float)(p0 >> 18), x0, acc);
        acc = fmaf((float)(p1 >> 18), x1, acc);
        acc = fmaf((float)(p2 >> 18), x2, acc);
        acc = fmaf((float)(p3 >> 18), x3, acc);
        acc = fmaf((float)(p4 >> 18), x4, acc);
        acc = fmaf((float)(p5 >> 18), x5, acc);
        acc = fmaf((float)(p6 >> 18), x6, acc);
        acc = fmaf((float)(p7 >> 18), x7, acc);
    }
    for (; e < s1; ++e) {
        unsigned p = pk[e];
        acc = fmaf((float)(p >> 18), __half2float(x[((p & 0x3FFFFu) << 6) + lane]), acc);
    }
    return acc * VAL_INV;
}

// remainder helper for the dual-row tail pull: 8-deep + scalar
__device__ __forceinline__ float pull_range(const unsigned* __restrict__ pk,
                                            const __half* __restrict__ x,
                                            int e, int s1, int lane, float acc) {
    for (; e + 8 <= s1; e += 8) {
        unsigned p0 = pk[e + 0], p1 = pk[e + 1], p2 = pk[e + 2], p3 = pk[e + 3];
        unsigned p4 = pk[e + 4], p5 = pk[e + 5], p6 = pk[e + 6], p7 = pk[e + 7];
        float x0 = __half2float(x[((p0 & 0x3FFFFu) << 6) + lane]);
        float x1 = __half2float(x[((p1 & 0x3FFFFu) << 6) + lane]);
        float x2 = __half2float(x[((p2 & 0x3FFFFu) << 6) + lane]);
        float x3 = __half2float(x[((p3 & 0x3FFFFu) << 6) + lane]);
        float x4 = __half2float(x[((p4 & 0x3FFFFu) << 6) + lane]);
        float x5 = __half2float(x[((p5 & 0x3FFFFu) << 6) + lane]);
        float x6 = __half2float(x[((p6 & 0x3FFFFu) << 6) + lane]);
        float x7 = __half2float(x[((p7 & 0x3FFFFu) << 6) + lane]);
        acc = fmaf((float)(p0 >> 18), x0, acc);
        acc = fmaf((float)(p1 >> 18), x1, acc);
        acc = fmaf((float)(p2 >> 18), x2, acc);
        acc = fmaf((float)(p3 >> 18), x3, acc);
        acc = fmaf((float)(p4 >> 18), x4, acc);
        acc = fmaf((float)(p5 >> 18), x5, acc);
        acc = fmaf((float)(p6 >> 18), x6, acc);
        acc = fmaf((float)(p7 >> 18), x7, acc);
    }
    for (; e < s1; ++e) {
        unsigned p = pk[e];
        acc = fmaf((float)(p >> 18), __half2float(x[((p & 0x3FFFFu) << 6) + lane]), acc);
    }
    return acc;
}

// ---------------------------------------------------------------------------
// pull SpMM: 4 rows (waves) per block
__global__ __launch_bounds__(256) void pull_kernel(const int* __restrict__ rowbeg,
                                                   const int* __restrict__ rowend,
                                                   const unsigned* __restrict__ pk,
                                                   const __half* __restrict__ x,
                                                   __half* __restrict__ y) {
    int lane = threadIdx.x & 63;
    int wv   = __builtin_amdgcn_readfirstlane(threadIdx.x >> 6);   // uniform
    int row  = blockIdx.x * 4 + wv;                                 // uniform
    if (row >= N_NODES) return;
    float acc = row_pull(rowbeg, rowend, pk, x, row, lane);
    y[((size_t)row << 6) + lane] = __float2half_rn(acc);
}

// ---------------------------------------------------------------------------
// mega-fused tail: one wave per batch element. Dual-interleaved layer-3 pulls
// for the user row AND item row (2x memory-level parallelism), combines
// l0(fp32 emb) + l1(nxt) + l2(cur) + l3 in registers, then softmax/sigmoid
// mix and writes gamma.
__global__ __launch_bounds__(256) void tail_kernel(const int* __restrict__ rowbeg,
                                                   const int* __restrict__ rowend,
                                                   const unsigned* __restrict__ pk,
                                                   const __half* __restrict__ cur,   // l2
                                                   const __half* __restrict__ nxt,   // l1
                                                   const float* __restrict__ eu,
                                                   const float* __restrict__ ei,
                                                   const float* __restrict__ exu,
                                                   const float* __restrict__ exi1,
                                                   const float* __restrict__ exi0,
                                                   const float* __restrict__ w_user,
                                                   const float* __restrict__ w_item,
                                                   const int* __restrict__ users,
                                                   const int* __restrict__ items,
                                                   const int* __restrict__ xijf,
                                                   float* __restrict__ out, int batch) {
    int lane = threadIdx.x & 63;
    int wv   = blockIdx.x * 4 + __builtin_amdgcn_readfirstlane(threadIdx.x >> 6);
    if (wv >= batch) return;
    int u    = users[wv];
    int it   = items[wv];
    int xf   = xijf[wv];
    int rowU = u;
    int rowI = NUM_USERS + it;

    // dual-interleaved layer-3 pulls from cur (l2): 16 gathers in flight
    int eA = rowbeg[rowU], sA = rowend[rowU];
    int eB = rowbeg[rowI], sB = rowend[rowI];
    float aU = 0.f, aI = 0.f;
    for (; eA + 8 <= sA && eB + 8 <= sB; eA += 8, eB += 8) {
        unsigned a0 = pk[eA + 0], a1 = pk[eA + 1], a2 = pk[eA + 2], a3 = pk[eA + 3];
        unsigned a4 = pk[eA + 4], a5 = pk[eA + 5], a6 = pk[eA + 6], a7 = pk[eA + 7];
        unsigned b0 = pk[eB + 0], b1 = pk[eB + 1], b2 = pk[eB + 2], b3 = pk[eB + 3];
        unsigned b4 = pk[eB + 4], b5 = pk[eB + 5], b6 = pk[eB + 6], b7 = pk[eB + 7];
        float xa0 = __half2float(cur[((a0 & 0x3FFFFu) << 6) + lane]);
        float xa1 = __half2float(cur[((a1 & 0x3FFFFu) << 6) + lane]);
        float xa2 = __half2float(cur[((a2 & 0x3FFFFu) << 6) + lane]);
        float xa3 = __half2float(cur[((a3 & 0x3FFFFu) << 6) + lane]);
        float xa4 = __half2float(cur[((a4 & 0x3FFFFu) << 6) + lane]);
        float xa5 = __half2float(cur[((a5 & 0x3FFFFu) << 6) + lane]);
        float xa6 = __half2float(cur[((a6 & 0x3FFFFu) << 6) + lane]);
        float xa7 = __half2float(cur[((a7 & 0x3FFFFu) << 6) + lane]);
        float xb0 = __half2float(cur[((b0 & 0x3FFFFu) << 6) + lane]);
        float xb1 = __half2float(cur[((b1 & 0x3FFFFu) << 6) + lane]);
        float xb2 = __half2float(cur[((b2 & 0x3FFFFu) << 6) + lane]);
        float xb3 = __half2float(cur[((b3 & 0x3FFFFu) << 6) + lane]);
        float xb4 = __half2float(cur[((b4 & 0x3FFFFu) << 6) + lane]);
        float xb5 = __half2float(cur[((b5 & 0x3FFFFu) << 6) + lane]);
        float xb6 = __half2float(cur[((b6 & 0x3FFFFu) << 6) + lane]);
        float xb7 = __half2float(cur[((b7 & 0x3FFFFu) << 6) + lane]);
        aU = fmaf((float)(a0 >> 18), xa0, aU);
        aU = fmaf((float)(a1 >> 18), xa1, aU);
        aU = fmaf((float)(a2 >> 18), xa2, aU);
        aU = fmaf((float)(a3 >> 18), xa3, aU);
        aU = fmaf((float)(a4 >> 18), xa4, aU);
        aU = fmaf((float)(a5 >> 18), xa5, aU);
        aU = fmaf((float)(a6 >> 18), xa6, aU);
        aU = fmaf((float)(a7 >> 18), xa7, aU);
        aI = fmaf((float)(b0 >> 18), xb0, aI);
        aI = fmaf((float)(b1 >> 18), xb1, aI);
        aI = fmaf((float)(b2 >> 18), xb2, aI);
        aI = fmaf((float)(b3 >> 18), xb3, aI);
        aI = fmaf((float)(b4 >> 18), xb4, aI);
        aI = fmaf((float)(b5 >> 18), xb5, aI);
        aI = fmaf((float)(b6 >> 18), xb6, aI);
        aI = fmaf((float)(b7 >> 18), xb7, aI);
    }
    aU = pull_range(pk, cur, eA, sA, lane, aU);
    aI = pull_range(pk, cur, eB, sB, lane, aI);
    float l3u = aU * VAL_INV;
    float l3i = aI * VAL_INV;

    float wu = w_user[0] * 0.25f;
    float wi = w_item[0] * 0.25f;

    float su = eu[((size_t)u  << 6) + lane]
             + __half2float(nxt[((size_t)rowU << 6) + lane])
             + __half2float(cur[((size_t)rowU << 6) + lane])
             + l3u;
    float si = ei[((size_t)it << 6) + lane]
             + __half2float(nxt[((size_t)rowI << 6) + lane])
             + __half2float(cur[((size_t)rowI << 6) + lane])
             + l3i;
    float ua = wu * su;
    float ia = wi * si;

    float ub = -INFINITY, ib = 0.f;
    if (lane < 16) {
        ub = exu[(size_t)u * 16 + lane];
        ib = xf ? exi1[(size_t)it * 16 + lane] : exi0[(size_t)it * 16 + lane];
    }

    float m = fmaxf(ua, ub);
    #pragma unroll
    for (int off = 32; off; off >>= 1) m = fmaxf(m, __shfl_xor(m, off));
    float ea = expf(ua - m);
    float eb = (lane < 16) ? expf(ub - m) : 0.f;
    float s = ea + eb;
    #pragma unroll
    for (int off = 32; off; off >>= 1) s += __shfl_xor(s, off);
    float inv = 1.f / s;

    float sa = 1.f / (1.f + expf(-ia));
    float sb = (lane < 16) ? 1.f / (1.f + expf(-ib)) : 0.f;

    float g = ea * inv * sa + eb * inv * sb;
    #pragma unroll
    for (int off = 32; off; off >>= 1) g += __shfl_xor(g, off);
    if (lane == 0) out[wv] = g;
}

// ---------------------------------------------------------------------------
extern "C" void kernel_launch(void* const* d_in, const int* in_sizes, int n_in,
                              void* d_out, int out_size, void* d_ws, size_t ws_size,
                              hipStream_t stream) {
    const float* emb_user = (const float*)d_in[0];
    const float* emb_item = (const float*)d_in[1];
    const float* exu      = (const float*)d_in[2];
    const float* exi1     = (const float*)d_in[3];
    const float* exi0     = (const float*)d_in[4];
    const float* w_user   = (const float*)d_in[5];
    const float* w_item   = (const float*)d_in[6];
    const float* gvals    = (const float*)d_in[7];
    const int*   grows    = (const int*)d_in[8];
    const int*   gcols    = (const int*)d_in[9];
    const int*   users    = (const int*)d_in[10];
    const int*   items    = (const int*)d_in[11];
    const int*   xijf     = (const int*)d_in[12];
    float*       out      = (float*)d_out;

    const int nnz   = in_sizes[7];
    const int batch = in_sizes[10];

    const size_t node_elems = (size_t)N_NODES * DIM;            // 9.6M
    const size_t PK8_BYTES  = (size_t)NBS * SLOTS * 8;          // 86.4 MB
    char* w = (char*)d_ws;
    uint2*    pk8   = (uint2*)w;                                // CSR-build scratch
    __half*   cur   = (__half*)w;                               // aliases pk8 (19.2 MB)
    __half*   nxt   = cur + node_elems;                         // aliases pk8 (19.2 MB)
    w += PK8_BYTES;
    unsigned* pk     = (unsigned*)w;              w += (size_t)NBS * PKSLOTS * 4;  // 26.7 MB
    int*      rowbeg = (int*)w;                   w += (size_t)N_NODES * 4;        // 0.6 MB
    int*      rowend = (int*)w;                   w += (size_t)N_NODES * 4;        // 0.6 MB
    int*      gcur   = (int*)w;                   w += (size_t)NBS * GPAD * 4;
    // total ~114.3 MB (< 115.2 MB proven in round 0)

    const int tb = 256;
    const int total4 = N_NODES * (DIM / 4);

    // ---- CSR build (pk8 live) ----
    gcur_init_kernel<<<(NBS + tb - 1) / tb, tb, 0, stream>>>(gcur);
    binned_scatter_kernel<<<SCAT_WGS, 256, 0, stream>>>(grows, gcols, gvals, gcur, pk8, nnz);
    bucket_build_kernel<<<NBS, BBT, 0, stream>>>(gcur, pk8, pk, rowbeg, rowend);

    // ---- dense init (pk8 dead; cur/nxt take over its space) ----
    copy_init_kernel<<<(total4 + tb - 1) / tb, tb, 0, stream>>>(
        (const float4*)emb_user, (const float4*)emb_item, (ushort4*)cur, total4);

    const int pull_blocks = (N_NODES + 3) / 4;       // 4 rows (waves) per block
    const int tail_blocks = (batch + 3) / 4;

    pull_kernel<<<pull_blocks, tb, 0, stream>>>(rowbeg, rowend, pk, cur, nxt);   // l1 = A*l0
    pull_kernel<<<pull_blocks, tb, 0, stream>>>(rowbeg, rowend, pk, nxt, cur);   // l2 = A*l1
    tail_kernel<<<tail_blocks, tb, 0, stream>>>(
        rowbeg, rowend, pk, cur, nxt, emb_user, emb_item,
        exu, exi1, exi0, w_user, w_item, users, items, xijf, out, batch);
}

// Round 10
// 515.779 us; speedup vs baseline: 1.0091x; 1.0091x over previous
//
#include <hip/hip_runtime.h>
#include <hip/hip_bf16.h>
#include <hip/hip_fp16.h>
#include <math.h>

#define NUM_USERS 100000
#define NUM_ITEMS 50000
#define N_NODES   150000
#define DIM       64
#define VAL_SCALE 16383.0f
#define VAL_INV   (1.0f / 16383.0f)

// scatter bucketing: 512 rows per bucket, fixed-capacity regions.
// ALL pk8 claims are 8-slot (64B) aligned -> no partial-line write
// amplification (r5/r6 lesson). CAP=17: ODD dword stride -> bucket bases
// spread across all 32 LDS banks (r9 lesson: CAP=12 aliases 8 banks).
// 1280 WGs: worst-case bucket use = 22.6K entries + 1280x7 drain + pads
// ~30.8K < SLOTS=32768 (r8 overflow lesson).
#define SSHIFT 9
#define SROWS  512
#define NBS    ((N_NODES + SROWS - 1) / SROWS)   // 293
#define CAP    17          // LDS buffer entries per bucket (odd -> bank spread)
#define FLUSH  8           // flush granularity (64B line of uint2)
#define SCAT_WGS 1280      // 5 WGs/CU x 256 CUs (30.3 KB LDS each)
#define GPAD   16          // pad global cursors to 64B lines
#define SLOTS  32768       // pk8 slots per bucket
#define PKSLOTS 22744      // final pk slots per bucket (mean + 6 sigma, x8 aligned)
#define SENTINEL 0xFFFFFFFFu
#define BBT 512            // bucket_build threads per WG (1:1 with SROWS)

// ---------------------------------------------------------------------------
// cur = fp16(concat(emb_user, emb_item)). total4 = N_NODES*16 (4 elems/thread)
__global__ void copy_init_kernel(const float4* __restrict__ eu, const float4* __restrict__ ei,
                                 ushort4* __restrict__ cur, int total4) {
    int i = blockIdx.x * blockDim.x + threadIdx.x;
    if (i >= total4) return;
    const int user_lim = NUM_USERS * (DIM / 4);
    float4 v = (i < user_lim) ? eu[i] : ei[i - user_lim];
    ushort4 h;
    h.x = __half_as_ushort(__float2half_rn(v.x));
    h.y = __half_as_ushort(__float2half_rn(v.y));
    h.z = __half_as_ushort(__float2half_rn(v.z));
    h.w = __half_as_ushort(__float2half_rn(v.w));
    cur[i] = h;
}

// ---------------------------------------------------------------------------
__global__ void gcur_init_kernel(int* __restrict__ gcur) {
    int b = blockIdx.x * blockDim.x + threadIdx.x;
    if (b < NBS) gcur[b * GPAD] = b * SLOTS;
}

// ---------------------------------------------------------------------------
// LDS-binned aggregated scatter (r7-proven): 2-edge vectorized input loads
// (int2/float2), uint4 16B line-flush stores, 8-slot (64B) aligned claims
// everywhere. NO per-edge global atomics (r6 lesson).
__global__ __launch_bounds__(256) void binned_scatter_kernel(
        const int* __restrict__ rows, const int* __restrict__ cols,
        const float* __restrict__ vals, int* __restrict__ gcur,
        uint2* __restrict__ pk8, int nnz) {
    __shared__ unsigned       lbufA[NBS * CAP];   // col | val<<18   (19.9 KB)
    __shared__ unsigned short lbufB[NBS * CAP];   // row-in-bucket    (10.0 KB)
    __shared__ int            lcur[NBS];          //                  (1.2 KB)
    int t = threadIdx.x;
    for (int i = t; i < NBS; i += 256) lcur[i] = 0;
    __syncthreads();

    int per_wg = (((nnz + (int)gridDim.x - 1) / (int)gridDim.x) + 1) & ~1;  // even
    int e0 = blockIdx.x * per_wg;
    int e1 = min(e0 + per_wg, nnz);

    #define PROC(rr, cc, vv) { \
        int r = (rr); \
        unsigned q = __float2uint_rn((vv) * VAL_SCALE); \
        unsigned ax = (unsigned)(cc) | (q << 18); \
        int b = r >> SSHIFT; \
        int pos = atomicAdd(&lcur[b], 1); \
        if (pos < CAP) { \
            lbufA[b * CAP + pos] = ax; \
            lbufB[b * CAP + pos] = (unsigned short)(r - (b << SSHIFT)); \
        } else { \
            atomicSub(&lcur[b], 1); \
            int p = atomicAdd(&gcur[b * GPAD], 8); \
            *(uint4*)(&pk8[p])     = make_uint4(ax, (unsigned)r, 0u, SENTINEL); \
            *(uint4*)(&pk8[p + 2]) = make_uint4(0u, SENTINEL, 0u, SENTINEL); \
            *(uint4*)(&pk8[p + 4]) = make_uint4(0u, SENTINEL, 0u, SENTINEL); \
            *(uint4*)(&pk8[p + 6]) = make_uint4(0u, SENTINEL, 0u, SENTINEL); \
        } }

    for (int base = e0; base < e1; base += 512) {
        int e = base + t * 2;
        if (e + 1 < e1) {
            int2   r2 = *(const int2*)(rows + e);
            int2   c2 = *(const int2*)(cols + e);
            float2 v2 = *(const float2*)(vals + e);
            PROC(r2.x, c2.x, v2.x)
            PROC(r2.y, c2.y, v2.y)
        } else if (e < e1) {
            PROC(rows[e], cols[e], vals[e])
        }
        __syncthreads();
        // flush all full 8-entry groups: one thread writes each 64B line (4x uint4)
        for (int b2 = t; b2 < NBS; b2 += 256) {
            int c = lcur[b2];
            if (c >= FLUSH) {
                int ng = c >> 3;
                int p = atomicAdd(&gcur[b2 * GPAD], ng * 8);
                unsigned rbase = (unsigned)(b2 << SSHIFT);
                for (int j = 0; j < ng * 8; j += 2) {
                    uint4 q = make_uint4(lbufA[b2 * CAP + j],     rbase + lbufB[b2 * CAP + j],
                                         lbufA[b2 * CAP + j + 1], rbase + lbufB[b2 * CAP + j + 1]);
                    *(uint4*)(&pk8[p + j]) = q;
                }
                int rem = c - ng * 8;
                for (int j = 0; j < rem; ++j) {
                    lbufA[b2 * CAP + j] = lbufA[b2 * CAP + ng * 8 + j];
                    lbufB[b2 * CAP + j] = lbufB[b2 * CAP + ng * 8 + j];
                }
                lcur[b2] = rem;
            }
        }
        __syncthreads();
    }
    // drain remainders (c <= 7): claim a full aligned line, pad with sentinels
    for (int b2 = t; b2 < NBS; b2 += 256) {
        int c = lcur[b2];
        if (c > 0) {
            int p = atomicAdd(&gcur[b2 * GPAD], 8);
            unsigned rbase = (unsigned)(b2 << SSHIFT);
            for (int j = 0; j < 8; j += 2) {
                unsigned a0 = (j     < c) ? lbufA[b2 * CAP + j]             : 0u;
                unsigned b0 = (j     < c) ? rbase + lbufB[b2 * CAP + j]     : SENTINEL;
                unsigned a1 = (j + 1 < c) ? lbufA[b2 * CAP + j + 1]         : 0u;
                unsigned b1 = (j + 1 < c) ? rbase + lbufB[b2 * CAP + j + 1] : SENTINEL;
                *(uint4*)(&pk8[p + j]) = make_uint4(a0, b0, a1, b1);
            }
        }
    }
}

// ---------------------------------------------------------------------------
// fused count + scan + CSR (r7-proven): 512 threads, uint4 paired-entry
// loads, 4-deep load pipeline, LDS atomics only. Two sequential reads of the
// bucket's pk8 segment; fixed per-bucket pk bases (b*PKSLOTS).
__global__ __launch_bounds__(BBT) void bucket_build_kernel(const int* __restrict__ gcur,
                                                           const uint2* __restrict__ pk8,
                                                           unsigned* __restrict__ pk,
                                                           int* __restrict__ rowbeg,
                                                           int* __restrict__ rowend) {
    __shared__ int lc[SROWS];    // counts, then cursors
    __shared__ int ps[SROWS];    // scan
    int b  = blockIdx.x;
    int r0 = b * SROWS;
    int nr = min(r0 + SROWS, N_NODES) - r0;
    int t  = threadIdx.x;        // 0..511, maps 1:1 to SROWS
    lc[t] = 0;
    __syncthreads();

    const uint4* p4 = (const uint4*)pk8;      // 2 entries per load
    int i0   = (b * SLOTS) >> 1;              // claims all 8-aligned -> pair-aligned
    int iend = gcur[b * GPAD] >> 1;

    #define CNT(q) { \
        if ((q).y != SENTINEL) atomicAdd(&lc[(int)(q).y - r0], 1); \
        if ((q).w != SENTINEL) atomicAdd(&lc[(int)(q).w - r0], 1); }

    int i = i0 + t;
    for (; i + 3 * BBT < iend; i += 4 * BBT) {
        uint4 qa = p4[i], qb = p4[i + BBT], qc = p4[i + 2 * BBT], qd = p4[i + 3 * BBT];
        CNT(qa) CNT(qb) CNT(qc) CNT(qd)
    }
    for (; i < iend; i += BBT) { uint4 qa = p4[i]; CNT(qa) }
    __syncthreads();

    int c = lc[t];
    ps[t] = c;
    __syncthreads();
    #pragma unroll
    for (int off = 1; off < SROWS; off <<= 1) {
        int u = (t >= off) ? ps[t - off] : 0;
        __syncthreads();
        ps[t] += u;
        __syncthreads();
    }
    int base = b * PKSLOTS + ps[t] - c;   // exclusive prefix
    if (t < nr) { rowbeg[r0 + t] = base; rowend[r0 + t] = base + c; }
    lc[t] = base;                          // cursor
    __syncthreads();

    #define PLC(q) { \
        if ((q).y != SENTINEL) { int p_ = atomicAdd(&lc[(int)(q).y - r0], 1); pk[p_] = (q).x; } \
        if ((q).w != SENTINEL) { int p_ = atomicAdd(&lc[(int)(q).w - r0], 1); pk[p_] = (q).z; } }

    i = i0 + t;
    for (; i + 3 * BBT < iend; i += 4 * BBT) {
        uint4 qa = p4[i], qb = p4[i + BBT], qc = p4[i + 2 * BBT], qd = p4[i + 3 * BBT];
        PLC(qa) PLC(qb) PLC(qc) PLC(qd)
    }
    for (; i < iend; i += BBT) { uint4 qa = p4[i]; PLC(qa) }
}

// ---------------------------------------------------------------------------
// edge-stream row reduction (v1 layout, proven fastest): wave-uniform row,
// lane = dim. pk[e] loads scalarize (row uniform); each edge is one 128B-
// contiguous wave gather. 16-deep unroll for latency hiding.
__device__ __forceinline__ float row_pull(const int* __restrict__ rowbeg,
                                          const int* __restrict__ rowend,
                                          const unsigned* __restrict__ pk,
                                          const __half* __restrict__ x,
                                          int row, int lane) {
    int s0 = rowbeg[row];
    int s1 = rowend[row];
    float acc = 0.f;
    int e = s0;
    for (; e + 16 <= s1; e += 16) {
        unsigned p0 = pk[e + 0],  p1 = pk[e + 1],  p2 = pk[e + 2],  p3 = pk[e + 3];
        unsigned p4 = pk[e + 4],  p5 = pk[e + 5],  p6 = pk[e + 6],  p7 = pk[e + 7];
        unsigned p8 = pk[e + 8],  p9 = pk[e + 9],  pA = pk[e + 10], pB = pk[e + 11];
        unsigned pC = pk[e + 12], pD = pk[e + 13], pE = pk[e + 14], pF = pk[e + 15];
        float x0 = __half2float(x[((p0 & 0x3FFFFu) << 6) + lane]);
        float x1 = __half2float(x[((p1 & 0x3FFFFu) << 6) + lane]);
        float x2 = __half2float(x[((p2 & 0x3FFFFu) << 6) + lane]);
        float x3 = __half2float(x[((p3 & 0x3FFFFu) << 6) + lane]);
        float x4 = __half2float(x[((p4 & 0x3FFFFu) << 6) + lane]);
        float x5 = __half2float(x[((p5 & 0x3FFFFu) << 6) + lane]);
        float x6 = __half2float(x[((p6 & 0x3FFFFu) << 6) + lane]);
        float x7 = __half2float(x[((p7 & 0x3FFFFu) << 6) + lane]);
        float x8 = __half2float(x[((p8 & 0x3FFFFu) << 6) + lane]);
        float x9 = __half2float(x[((p9 & 0x3FFFFu) << 6) + lane]);
        float xA = __half2float(x[((pA & 0x3FFFFu) << 6) + lane]);
        float xB = __half2float(x[((pB & 0x3FFFFu) << 6) + lane]);
        float xC = __half2float(x[((pC & 0x3FFFFu) << 6) + lane]);
        float xD = __half2float(x[((pD & 0x3FFFFu) << 6) + lane]);
        float xE = __half2float(x[((pE & 0x3FFFFu) << 6) + lane]);
        float xF = __half2float(x[((pF & 0x3FFFFu) << 6) + lane]);
        acc = fmaf((float)(p0 >> 18), x0, acc);
        acc = fmaf((float)(p1 >> 18), x1, acc);
        acc = fmaf((float)(p2 >> 18), x2, acc);
        acc = fmaf((float)(p3 >> 18), x3, acc);
        acc = fmaf((float)(p4 >> 18), x4, acc);
        acc = fmaf((float)(p5 >> 18), x5, acc);
        acc = fmaf((float)(p6 >> 18), x6, acc);
        acc = fmaf((float)(p7 >> 18), x7, acc);
        acc = fmaf((float)(p8 >> 18), x8, acc);
        acc = fmaf((float)(p9 >> 18), x9, acc);
        acc = fmaf((float)(pA >> 18), xA, acc);
        acc = fmaf((float)(pB >> 18), xB, acc);
        acc = fmaf((float)(pC >> 18), xC, acc);
        acc = fmaf((float)(pD >> 18), xD, acc);
        acc = fmaf((float)(pE >> 18), xE, acc);
        acc = fmaf((float)(pF >> 18), xF, acc);
    }
    for (; e + 8 <= s1; e += 8) {
        unsigned p0 = pk[e + 0], p1 = pk[e + 1], p2 = pk[e + 2], p3 = pk[e + 3];
        unsigned p4 = pk[e + 4], p5 = pk[e + 5], p6 = pk[e + 6], p7 = pk[e + 7];
        float x0 = __half2float(x[((p0 & 0x3FFFFu) << 6) + lane]);
        float x1 = __half2float(x[((p1 & 0x3FFFFu) << 6) + lane]);
        float x2 = __half2float(x[((p2 & 0x3FFFFu) << 6) + lane]);
        float x3 = __half2float(x[((p3 & 0x3FFFFu) << 6) + lane]);
        float x4 = __half2float(x[((p4 & 0x3FFFFu) << 6) + lane]);
        float x5 = __half2float(x[((p5 & 0x3FFFFu) << 6) + lane]);
        float x6 = __half2float(x[((p6 & 0x3FFFFu) << 6) + lane]);
        float x7 = __half2float(x[((p7 & 0x3FFFFu) << 6) + lane]);
        acc = fmaf((float)(p0 >> 18), x0, acc);
        acc = fmaf((float)(p1 >> 18), x1, acc);
        acc = fmaf((float)(p2 >> 18), x2, acc);
        acc = fmaf((float)(p3 >> 18), x3, acc);
        acc = fmaf((float)(p4 >> 18), x4, acc);
        acc = fmaf((float)(p5 >> 18), x5, acc);
        acc = fmaf((float)(p6 >> 18), x6, acc);
        acc = fmaf((float)(p7 >> 18), x7, acc);
    }
    for (; e < s1; ++e) {
        unsigned p = pk[e];
        acc = fmaf((float)(p >> 18), __half2float(x[((p & 0x3FFFFu) << 6) + lane]), acc);
    }
    return acc * VAL_INV;
}

// remainder helper for the dual-row tail pull: 8-deep + scalar
__device__ __forceinline__ float pull_range(const unsigned* __restrict__ pk,
                                            const __half* __restrict__ x,
                                            int e, int s1, int lane, float acc) {
    for (; e + 8 <= s1; e += 8) {
        unsigned p0 = pk[e + 0], p1 = pk[e + 1], p2 = pk[e + 2], p3 = pk[e + 3];
        unsigned p4 = pk[e + 4], p5 = pk[e + 5], p6 = pk[e + 6], p7 = pk[e + 7];
        float x0 = __half2float(x[((p0 & 0x3FFFFu) << 6) + lane]);
        float x1 = __half2float(x[((p1 & 0x3FFFFu) << 6) + lane]);
        float x2 = __half2float(x[((p2 & 0x3FFFFu) << 6) + lane]);
        float x3 = __half2float(x[((p3 & 0x3FFFFu) << 6) + lane]);
        float x4 = __half2float(x[((p4 & 0x3FFFFu) << 6) + lane]);
        float x5 = __half2float(x[((p5 & 0x3FFFFu) << 6) + lane]);
        float x6 = __half2float(x[((p6 & 0x3FFFFu) << 6) + lane]);
        float x7 = __half2float(x[((p7 & 0x3FFFFu) << 6) + lane]);
        acc = fmaf((float)(p0 >> 18), x0, acc);
        acc = fmaf((float)(p1 >> 18), x1, acc);
        acc = fmaf((float)(p2 >> 18), x2, acc);
        acc = fmaf((float)(p3 >> 18), x3, acc);
        acc = fmaf((float)(p4 >> 18), x4, acc);
        acc = fmaf((float)(p5 >> 18), x5, acc);
        acc = fmaf((float)(p6 >> 18), x6, acc);
        acc = fmaf((float)(p7 >> 18), x7, acc);
    }
    for (; e < s1; ++e) {
        unsigned p = pk[e];
        acc = fmaf((float)(p >> 18), __half2float(x[((p & 0x3FFFFu) << 6) + lane]), acc);
    }
    return acc;
}

// ---------------------------------------------------------------------------
// pull SpMM: 4 rows (waves) per block
__global__ __launch_bounds__(256) void pull_kernel(const int* __restrict__ rowbeg,
                                                   const int* __restrict__ rowend,
                                                   const unsigned* __restrict__ pk,
                                                   const __half* __restrict__ x,
                                                   __half* __restrict__ y) {
    int lane = threadIdx.x & 63;
    int wv   = __builtin_amdgcn_readfirstlane(threadIdx.x >> 6);   // uniform
    int row  = blockIdx.x * 4 + wv;                                 // uniform
    if (row >= N_NODES) return;
    float acc = row_pull(rowbeg, rowend, pk, x, row, lane);
    y[((size_t)row << 6) + lane] = __float2half_rn(acc);
}

// ---------------------------------------------------------------------------
// mega-fused tail: one wave per batch element. Dual-interleaved layer-3 pulls
// for the user row AND item row (2x memory-level parallelism), combines
// l0(fp32 emb) + l1(nxt) + l2(cur) + l3 in registers, then softmax/sigmoid
// mix and writes gamma.
__global__ __launch_bounds__(256) void tail_kernel(const int* __restrict__ rowbeg,
                                                   const int* __restrict__ rowend,
                                                   const unsigned* __restrict__ pk,
                                                   const __half* __restrict__ cur,   // l2
                                                   const __half* __restrict__ nxt,   // l1
                                                   const float* __restrict__ eu,
                                                   const float* __restrict__ ei,
                                                   const float* __restrict__ exu,
                                                   const float* __restrict__ exi1,
                                                   const float* __restrict__ exi0,
                                                   const float* __restrict__ w_user,
                                                   const float* __restrict__ w_item,
                                                   const int* __restrict__ users,
                                                   const int* __restrict__ items,
                                                   const int* __restrict__ xijf,
                                                   float* __restrict__ out, int batch) {
    int lane = threadIdx.x & 63;
    int wv   = blockIdx.x * 4 + __builtin_amdgcn_readfirstlane(threadIdx.x >> 6);
    if (wv >= batch) return;
    int u    = users[wv];
    int it   = items[wv];
    int xf   = xijf[wv];
    int rowU = u;
    int rowI = NUM_USERS + it;

    // dual-interleaved layer-3 pulls from cur (l2): 16 gathers in flight
    int eA = rowbeg[rowU], sA = rowend[rowU];
    int eB = rowbeg[rowI], sB = rowend[rowI];
    float aU = 0.f, aI = 0.f;
    for (; eA + 8 <= sA && eB + 8 <= sB; eA += 8, eB += 8) {
        unsigned a0 = pk[eA + 0], a1 = pk[eA + 1], a2 = pk[eA + 2], a3 = pk[eA + 3];
        unsigned a4 = pk[eA + 4], a5 = pk[eA + 5], a6 = pk[eA + 6], a7 = pk[eA + 7];
        unsigned b0 = pk[eB + 0], b1 = pk[eB + 1], b2 = pk[eB + 2], b3 = pk[eB + 3];
        unsigned b4 = pk[eB + 4], b5 = pk[eB + 5], b6 = pk[eB + 6], b7 = pk[eB + 7];
        float xa0 = __half2float(cur[((a0 & 0x3FFFFu) << 6) + lane]);
        float xa1 = __half2float(cur[((a1 & 0x3FFFFu) << 6) + lane]);
        float xa2 = __half2float(cur[((a2 & 0x3FFFFu) << 6) + lane]);
        float xa3 = __half2float(cur[((a3 & 0x3FFFFu) << 6) + lane]);
        float xa4 = __half2float(cur[((a4 & 0x3FFFFu) << 6) + lane]);
        float xa5 = __half2float(cur[((a5 & 0x3FFFFu) << 6) + lane]);
        float xa6 = __half2float(cur[((a6 & 0x3FFFFu) << 6) + lane]);
        float xa7 = __half2float(cur[((a7 & 0x3FFFFu) << 6) + lane]);
        float xb0 = __half2float(cur[((b0 & 0x3FFFFu) << 6) + lane]);
        float xb1 = __half2float(cur[((b1 & 0x3FFFFu) << 6) + lane]);
        float xb2 = __half2float(cur[((b2 & 0x3FFFFu) << 6) + lane]);
        float xb3 = __half2float(cur[((b3 & 0x3FFFFu) << 6) + lane]);
        float xb4 = __half2float(cur[((b4 & 0x3FFFFu) << 6) + lane]);
        float xb5 = __half2float(cur[((b5 & 0x3FFFFu) << 6) + lane]);
        float xb6 = __half2float(cur[((b6 & 0x3FFFFu) << 6) + lane]);
        float xb7 = __half2float(cur[((b7 & 0x3FFFFu) << 6) + lane]);
        aU = fmaf((float)(a0 >> 18), xa0, aU);
        aU = fmaf((float)(a1 >> 18), xa1, aU);
        aU = fmaf((float)(a2 >> 18), xa2, aU);
        aU = fmaf((float)(a3 >> 18), xa3, aU);
        aU = fmaf((float)(a4 >> 18), xa4, aU);
        aU = fmaf((float)(a5 >> 18), xa5, aU);
        aU = fmaf((float)(a6 >> 18), xa6, aU);
        aU = fmaf((float)(a7 >> 18), xa7, aU);
        aI = fmaf((float)(b0 >> 18), xb0, aI);
        aI = fmaf((float)(b1 >> 18), xb1, aI);
        aI = fmaf((float)(b2 >> 18), xb2, aI);
        aI = fmaf((float)(b3 >> 18), xb3, aI);
        aI = fmaf((float)(b4 >> 18), xb4, aI);
        aI = fmaf((float)(b5 >> 18), xb5, aI);
        aI = fmaf((float)(b6 >> 18), xb6, aI);
        aI = fmaf((float)(b7 >> 18), xb7, aI);
    }
    aU = pull_range(pk, cur, eA, sA, lane, aU);
    aI = pull_range(pk, cur, eB, sB, lane, aI);
    float l3u = aU * VAL_INV;
    float l3i = aI * VAL_INV;

    float wu = w_user[0] * 0.25f;
    float wi = w_item[0] * 0.25f;

    float su = eu[((size_t)u  << 6) + lane]
             + __half2float(nxt[((size_t)rowU << 6) + lane])
             + __half2float(cur[((size_t)rowU << 6) + lane])
             + l3u;
    float si = ei[((size_t)it << 6) + lane]
             + __half2float(nxt[((size_t)rowI << 6) + lane])
             + __half2float(cur[((size_t)rowI << 6) + lane])
             + l3i;
    float ua = wu * su;
    float ia = wi * si;

    float ub = -INFINITY, ib = 0.f;
    if (lane < 16) {
        ub = exu[(size_t)u * 16 + lane];
        ib = xf ? exi1[(size_t)it * 16 + lane] : exi0[(size_t)it * 16 + lane];
    }

    float m = fmaxf(ua, ub);
    #pragma unroll
    for (int off = 32; off; off >>= 1) m = fmaxf(m, __shfl_xor(m, off));
    float ea = expf(ua - m);
    float eb = (lane < 16) ? expf(ub - m) : 0.f;
    float s = ea + eb;
    #pragma unroll
    for (int off = 32; off; off >>= 1) s += __shfl_xor(s, off);
    float inv = 1.f / s;

    float sa = 1.f / (1.f + expf(-ia));
    float sb = (lane < 16) ? 1.f / (1.f + expf(-ib)) : 0.f;

    float g = ea * inv * sa + eb * inv * sb;
    #pragma unroll
    for (int off = 32; off; off >>= 1) g += __shfl_xor(g, off);
    if (lane == 0) out[wv] = g;
}

// ---------------------------------------------------------------------------
extern "C" void kernel_launch(void* const* d_in, const int* in_sizes, int n_in,
                              void* d_out, int out_size, void* d_ws, size_t ws_size,
                              hipStream_t stream) {
    const float* emb_user = (const float*)d_in[0];
    const float* emb_item = (const float*)d_in[1];
    const float* exu      = (const float*)d_in[2];
    const float* exi1     = (const float*)d_in[3];
    const float* exi0     = (const float*)d_in[4];
    const float* w_user   = (const float*)d_in[5];
    const float* w_item   = (const float*)d_in[6];
    const float* gvals    = (const float*)d_in[7];
    const int*   grows    = (const int*)d_in[8];
    const int*   gcols    = (const int*)d_in[9];
    const int*   users    = (const int*)d_in[10];
    const int*   items    = (const int*)d_in[11];
    const int*   xijf     = (const int*)d_in[12];
    float*       out      = (float*)d_out;

    const int nnz   = in_sizes[7];
    const int batch = in_sizes[10];

    const size_t node_elems = (size_t)N_NODES * DIM;            // 9.6M
    const size_t PK8_BYTES  = (size_t)NBS * SLOTS * 8;          // 76.8 MB
    char* w = (char*)d_ws;
    uint2*    pk8   = (uint2*)w;                                // CSR-build scratch
    __half*   cur   = (__half*)w;                               // aliases pk8 (19.2 MB)
    __half*   nxt   = cur + node_elems;                         // aliases pk8 (19.2 MB)
    w += PK8_BYTES;
    unsigned* pk     = (unsigned*)w;              w += (size_t)NBS * PKSLOTS * 4;  // 26.7 MB
    int*      rowbeg = (int*)w;                   w += (size_t)N_NODES * 4;        // 0.6 MB
    int*      rowend = (int*)w;                   w += (size_t)N_NODES * 4;        // 0.6 MB
    int*      gcur   = (int*)w;                   w += (size_t)NBS * GPAD * 4;
    // total ~104.7 MB (< 115.2 MB proven in round 0)

    const int tb = 256;
    const int total4 = N_NODES * (DIM / 4);

    // ---- CSR build (pk8 live) ----
    gcur_init_kernel<<<(NBS + tb - 1) / tb, tb, 0, stream>>>(gcur);
    binned_scatter_kernel<<<SCAT_WGS, 256, 0, stream>>>(grows, gcols, gvals, gcur, pk8, nnz);
    bucket_build_kernel<<<NBS, BBT, 0, stream>>>(gcur, pk8, pk, rowbeg, rowend);

    // ---- dense init (pk8 dead; cur/nxt take over its space) ----
    copy_init_kernel<<<(total4 + tb - 1) / tb, tb, 0, stream>>>(
        (const float4*)emb_user, (const float4*)emb_item, (ushort4*)cur, total4);

    const int pull_blocks = (N_NODES + 3) / 4;       // 4 rows (waves) per block
    const int tail_blocks = (batch + 3) / 4;

    pull_kernel<<<pull_blocks, tb, 0, stream>>>(rowbeg, rowend, pk, cur, nxt);   // l1 = A*l0
    pull_kernel<<<pull_blocks, tb, 0, stream>>>(rowbeg, rowend, pk, nxt, cur);   // l2 = A*l1
    tail_kernel<<<tail_blocks, tb, 0, stream>>>(
        rowbeg, rowend, pk, cur, nxt, emb_user, emb_item,
        exu, exi1, exi0, w_user, w_item, users, items, xijf, out, batch);
}

// Round 11
// 506.241 us; speedup vs baseline: 1.0281x; 1.0188x over previous
//
#include <hip/hip_runtime.h>
#include <hip/hip_bf16.h>
#include <hip/hip_fp16.h>
#include <math.h>

#define NUM_USERS 100000
#define NUM_ITEMS 50000
#define N_NODES   150000
#define DIM       64
#define VAL_SCALE 16383.0f
#define VAL_INV   (1.0f / 16383.0f)

// scatter bucketing: 512 rows per bucket, fixed-capacity regions.
// Split-stream staging (r11): axbuf (4B payload) + rowbuf (2B bucket-local
// row, sentinel 0xFFFF). Count pass reads ONLY rowbuf (15MB vs 94MB).
// ALL claims are 8-slot granular -> ax chunks 32B-aligned, row chunks
// 16B-aligned: no partial-line write amplification (r5/r6 lesson).
// CAP=17: odd stride -> LDS bank spread (r9 lesson). 1280 WGs: worst-case
// bucket use ~30.8K < SLOTS=32768 (r8 overflow lesson).
#define SSHIFT 9
#define SROWS  512
#define NBS    ((N_NODES + SROWS - 1) / SROWS)   // 293
#define CAP    17          // LDS buffer entries per bucket (odd -> bank spread)
#define FLUSH  8           // flush granularity (8 slots)
#define SCAT_WGS 1280      // 5 WGs/CU x 256 CUs (31 KB LDS each)
#define GPAD   16          // pad global cursors to 64B lines
#define SLOTS  32768       // staging slots per bucket
#define PKSLOTS 22744      // final pk slots per bucket (mean + 6 sigma, x8 aligned)
#define SENTR  0xFFFFu     // rowbuf sentinel
#define BBT 512            // bucket_build threads per WG (1:1 with SROWS)

// ---------------------------------------------------------------------------
// cur = fp16(concat(emb_user, emb_item)). total4 = N_NODES*16 (4 elems/thread)
__global__ void copy_init_kernel(const float4* __restrict__ eu, const float4* __restrict__ ei,
                                 ushort4* __restrict__ cur, int total4) {
    int i = blockIdx.x * blockDim.x + threadIdx.x;
    if (i >= total4) return;
    const int user_lim = NUM_USERS * (DIM / 4);
    float4 v = (i < user_lim) ? eu[i] : ei[i - user_lim];
    ushort4 h;
    h.x = __half_as_ushort(__float2half_rn(v.x));
    h.y = __half_as_ushort(__float2half_rn(v.y));
    h.z = __half_as_ushort(__float2half_rn(v.z));
    h.w = __half_as_ushort(__float2half_rn(v.w));
    cur[i] = h;
}

// ---------------------------------------------------------------------------
__global__ void gcur_init_kernel(int* __restrict__ gcur) {
    int b = blockIdx.x * blockDim.x + threadIdx.x;
    if (b < NBS) gcur[b * GPAD] = b * SLOTS;
}

// ---------------------------------------------------------------------------
// LDS-binned aggregated scatter, split-stream: 2-edge vectorized input loads,
// uint4 flush stores to both streams, 8-slot granular claims. NO per-edge
// global atomics (r6 lesson).
__global__ __launch_bounds__(256) void binned_scatter_kernel(
        const int* __restrict__ rows, const int* __restrict__ cols,
        const float* __restrict__ vals, int* __restrict__ gcur,
        unsigned* __restrict__ axbuf, unsigned short* __restrict__ rowbuf,
        int nnz) {
    __shared__ unsigned       lbufA[NBS * CAP];   // col | val<<18   (19.9 KB)
    __shared__ unsigned short lbufB[NBS * CAP];   // row-in-bucket    (10.0 KB)
    __shared__ int            lcur[NBS];          //                  (1.2 KB)
    int t = threadIdx.x;
    for (int i = t; i < NBS; i += 256) lcur[i] = 0;
    __syncthreads();

    int per_wg = (((nnz + (int)gridDim.x - 1) / (int)gridDim.x) + 1) & ~1;  // even
    int e0 = blockIdx.x * per_wg;
    int e1 = min(e0 + per_wg, nnz);

    #define PROC(rr, cc, vv) { \
        int r = (rr); \
        unsigned q = __float2uint_rn((vv) * VAL_SCALE); \
        unsigned ax = (unsigned)(cc) | (q << 18); \
        int b = r >> SSHIFT; \
        int pos = atomicAdd(&lcur[b], 1); \
        if (pos < CAP) { \
            lbufA[b * CAP + pos] = ax; \
            lbufB[b * CAP + pos] = (unsigned short)(r - (b << SSHIFT)); \
        } else { \
            atomicSub(&lcur[b], 1); \
            int p = atomicAdd(&gcur[b * GPAD], 8); \
            *(uint4*)(&axbuf[p])     = make_uint4(ax, 0u, 0u, 0u); \
            *(uint4*)(&axbuf[p + 4]) = make_uint4(0u, 0u, 0u, 0u); \
            *(uint4*)(&rowbuf[p])    = make_uint4( \
                (unsigned)(r - (b << SSHIFT)) | 0xFFFF0000u, \
                0xFFFFFFFFu, 0xFFFFFFFFu, 0xFFFFFFFFu); \
        } }

    for (int base = e0; base < e1; base += 512) {
        int e = base + t * 2;
        if (e + 1 < e1) {
            int2   r2 = *(const int2*)(rows + e);
            int2   c2 = *(const int2*)(cols + e);
            float2 v2 = *(const float2*)(vals + e);
            PROC(r2.x, c2.x, v2.x)
            PROC(r2.y, c2.y, v2.y)
        } else if (e < e1) {
            PROC(rows[e], cols[e], vals[e])
        }
        __syncthreads();
        // flush all full 8-entry groups: one thread writes each group
        // (2x uint4 ax + 1x uint4 packed rows)
        for (int b2 = t; b2 < NBS; b2 += 256) {
            int c = lcur[b2];
            if (c >= FLUSH) {
                int ng = c >> 3;
                int p = atomicAdd(&gcur[b2 * GPAD], ng * 8);
                for (int j = 0; j < ng * 8; j += 4) {
                    *(uint4*)(&axbuf[p + j]) = make_uint4(
                        lbufA[b2 * CAP + j],     lbufA[b2 * CAP + j + 1],
                        lbufA[b2 * CAP + j + 2], lbufA[b2 * CAP + j + 3]);
                }
                for (int j = 0; j < ng * 8; j += 8) {
                    unsigned w0 = (unsigned)lbufB[b2 * CAP + j]     | ((unsigned)lbufB[b2 * CAP + j + 1] << 16);
                    unsigned w1 = (unsigned)lbufB[b2 * CAP + j + 2] | ((unsigned)lbufB[b2 * CAP + j + 3] << 16);
                    unsigned w2 = (unsigned)lbufB[b2 * CAP + j + 4] | ((unsigned)lbufB[b2 * CAP + j + 5] << 16);
                    unsigned w3 = (unsigned)lbufB[b2 * CAP + j + 6] | ((unsigned)lbufB[b2 * CAP + j + 7] << 16);
                    *(uint4*)(&rowbuf[p + j]) = make_uint4(w0, w1, w2, w3);
                }
                int rem = c - ng * 8;
                for (int j = 0; j < rem; ++j) {
                    lbufA[b2 * CAP + j] = lbufA[b2 * CAP + ng * 8 + j];
                    lbufB[b2 * CAP + j] = lbufB[b2 * CAP + ng * 8 + j];
                }
                lcur[b2] = rem;
            }
        }
        __syncthreads();
    }
    // drain remainders (c <= 7): claim a full 8-slot group, pad with sentinels
    for (int b2 = t; b2 < NBS; b2 += 256) {
        int c = lcur[b2];
        if (c > 0) {
            int p = atomicAdd(&gcur[b2 * GPAD], 8);
            unsigned av[8]; unsigned rv[8];
            #pragma unroll
            for (int j = 0; j < 8; ++j) {
                av[j] = (j < c) ? lbufA[b2 * CAP + j] : 0u;
                rv[j] = (j < c) ? (unsigned)lbufB[b2 * CAP + j] : SENTR;
            }
            *(uint4*)(&axbuf[p])     = make_uint4(av[0], av[1], av[2], av[3]);
            *(uint4*)(&axbuf[p + 4]) = make_uint4(av[4], av[5], av[6], av[7]);
            *(uint4*)(&rowbuf[p])    = make_uint4(rv[0] | (rv[1] << 16),
                                                  rv[2] | (rv[3] << 16),
                                                  rv[4] | (rv[5] << 16),
                                                  rv[6] | (rv[7] << 16));
        }
    }
}

// ---------------------------------------------------------------------------
// fused count + scan + CSR, split-stream: count pass reads ONLY the 2B row
// stream (8 entries per uint4, ~6x less traffic than the old 8B entries);
// place pass reads row uint4 + 2 ax uint4 per 8 entries. LDS atomics only.
__global__ __launch_bounds__(BBT) void bucket_build_kernel(const int* __restrict__ gcur,
                                                           const unsigned* __restrict__ axbuf,
                                                           const unsigned short* __restrict__ rowbuf,
                                                           unsigned* __restrict__ pk,
                                                           int* __restrict__ rowbeg,
                                                           int* __restrict__ rowend) {
    __shared__ int lc[SROWS];    // counts, then cursors
    __shared__ int ps[SROWS];    // scan
    int b  = blockIdx.x;
    int r0 = b * SROWS;
    int nr = min(r0 + SROWS, N_NODES) - r0;
    int t  = threadIdx.x;        // 0..511, maps 1:1 to SROWS
    lc[t] = 0;
    __syncthreads();

    const uint4* r4 = (const uint4*)rowbuf;   // 8 entries per load
    const uint4* a4 = (const uint4*)axbuf;    // 4 entries per load
    int i0   = (b * SLOTS) >> 3;              // claims all multiples of 8
    int iend = gcur[b * GPAD] >> 3;

    #define CNT8(q) { \
        unsigned h; \
        h = (q).x & 0xFFFFu; if (h != SENTR) atomicAdd(&lc[h], 1); \
        h = (q).x >> 16;     if (h != SENTR) atomicAdd(&lc[h], 1); \
        h = (q).y & 0xFFFFu; if (h != SENTR) atomicAdd(&lc[h], 1); \
        h = (q).y >> 16;     if (h != SENTR) atomicAdd(&lc[h], 1); \
        h = (q).z & 0xFFFFu; if (h != SENTR) atomicAdd(&lc[h], 1); \
        h = (q).z >> 16;     if (h != SENTR) atomicAdd(&lc[h], 1); \
        h = (q).w & 0xFFFFu; if (h != SENTR) atomicAdd(&lc[h], 1); \
        h = (q).w >> 16;     if (h != SENTR) atomicAdd(&lc[h], 1); }

    int i = i0 + t;
    for (; i + BBT < iend; i += 2 * BBT) {
        uint4 q1 = r4[i], q2 = r4[i + BBT];
        CNT8(q1) CNT8(q2)
    }
    for (; i < iend; i += BBT) { uint4 q1 = r4[i]; CNT8(q1) }
    __syncthreads();

    int c = lc[t];
    ps[t] = c;
    __syncthreads();
    #pragma unroll
    for (int off = 1; off < SROWS; off <<= 1) {
        int u = (t >= off) ? ps[t - off] : 0;
        __syncthreads();
        ps[t] += u;
        __syncthreads();
    }
    int base = b * PKSLOTS + ps[t] - c;   // exclusive prefix
    if (t < nr) { rowbeg[r0 + t] = base; rowend[r0 + t] = base + c; }
    lc[t] = base;                          // cursor
    __syncthreads();

    #define PLC2(h, v) { \
        if ((h) != SENTR) { int p_ = atomicAdd(&lc[(h)], 1); pk[p_] = (v); } }

    i = i0 + t;
    for (; i < iend; i += BBT) {
        uint4 rq = r4[i];
        uint4 a0 = a4[2 * i], a1 = a4[2 * i + 1];
        PLC2(rq.x & 0xFFFFu, a0.x)
        PLC2(rq.x >> 16,     a0.y)
        PLC2(rq.y & 0xFFFFu, a0.z)
        PLC2(rq.y >> 16,     a0.w)
        PLC2(rq.z & 0xFFFFu, a1.x)
        PLC2(rq.z >> 16,     a1.y)
        PLC2(rq.w & 0xFFFFu, a1.z)
        PLC2(rq.w >> 16,     a1.w)
    }
}

// ---------------------------------------------------------------------------
// edge-stream row reduction (v1 layout, proven fastest): wave-uniform row,
// lane = dim. pk[e] loads scalarize (row uniform); each edge is one 128B-
// contiguous wave gather. 16-deep unroll for latency hiding.
__device__ __forceinline__ float row_pull(const int* __restrict__ rowbeg,
                                          const int* __restrict__ rowend,
                                          const unsigned* __restrict__ pk,
                                          const __half* __restrict__ x,
                                          int row, int lane) {
    int s0 = rowbeg[row];
    int s1 = rowend[row];
    float acc = 0.f;
    int e = s0;
    for (; e + 16 <= s1; e += 16) {
        unsigned p0 = pk[e + 0],  p1 = pk[e + 1],  p2 = pk[e + 2],  p3 = pk[e + 3];
        unsigned p4 = pk[e + 4],  p5 = pk[e + 5],  p6 = pk[e + 6],  p7 = pk[e + 7];
        unsigned p8 = pk[e + 8],  p9 = pk[e + 9],  pA = pk[e + 10], pB = pk[e + 11];
        unsigned pC = pk[e + 12], pD = pk[e + 13], pE = pk[e + 14], pF = pk[e + 15];
        float x0 = __half2float(x[((p0 & 0x3FFFFu) << 6) + lane]);
        float x1 = __half2float(x[((p1 & 0x3FFFFu) << 6) + lane]);
        float x2 = __half2float(x[((p2 & 0x3FFFFu) << 6) + lane]);
        float x3 = __half2float(x[((p3 & 0x3FFFFu) << 6) + lane]);
        float x4 = __half2float(x[((p4 & 0x3FFFFu) << 6) + lane]);
        float x5 = __half2float(x[((p5 & 0x3FFFFu) << 6) + lane]);
        float x6 = __half2float(x[((p6 & 0x3FFFFu) << 6) + lane]);
        float x7 = __half2float(x[((p7 & 0x3FFFFu) << 6) + lane]);
        float x8 = __half2float(x[((p8 & 0x3FFFFu) << 6) + lane]);
        float x9 = __half2float(x[((p9 & 0x3FFFFu) << 6) + lane]);
        float xA = __half2float(x[((pA & 0x3FFFFu) << 6) + lane]);
        float xB = __half2float(x[((pB & 0x3FFFFu) << 6) + lane]);
        float xC = __half2float(x[((pC & 0x3FFFFu) << 6) + lane]);
        float xD = __half2float(x[((pD & 0x3FFFFu) << 6) + lane]);
        float xE = __half2float(x[((pE & 0x3FFFFu) << 6) + lane]);
        float xF = __half2float(x[((pF & 0x3FFFFu) << 6) + lane]);
        acc = fmaf((float)(p0 >> 18), x0, acc);
        acc = fmaf((float)(p1 >> 18), x1, acc);
        acc = fmaf((float)(p2 >> 18), x2, acc);
        acc = fmaf((float)(p3 >> 18), x3, acc);
        acc = fmaf((float)(p4 >> 18), x4, acc);
        acc = fmaf((float)(p5 >> 18), x5, acc);
        acc = fmaf((float)(p6 >> 18), x6, acc);
        acc = fmaf((float)(p7 >> 18), x7, acc);
        acc = fmaf((float)(p8 >> 18), x8, acc);
        acc = fmaf((float)(p9 >> 18), x9, acc);
        acc = fmaf((float)(pA >> 18), xA, acc);
        acc = fmaf((float)(pB >> 18), xB, acc);
        acc = fmaf((float)(pC >> 18), xC, acc);
        acc = fmaf((float)(pD >> 18), xD, acc);
        acc = fmaf((float)(pE >> 18), xE, acc);
        acc = fmaf((float)(pF >> 18), xF, acc);
    }
    for (; e + 8 <= s1; e += 8) {
        unsigned p0 = pk[e + 0], p1 = pk[e + 1], p2 = pk[e + 2], p3 = pk[e + 3];
        unsigned p4 = pk[e + 4], p5 = pk[e + 5], p6 = pk[e + 6], p7 = pk[e + 7];
        float x0 = __half2float(x[((p0 & 0x3FFFFu) << 6) + lane]);
        float x1 = __half2float(x[((p1 & 0x3FFFFu) << 6) + lane]);
        float x2 = __half2float(x[((p2 & 0x3FFFFu) << 6) + lane]);
        float x3 = __half2float(x[((p3 & 0x3FFFFu) << 6) + lane]);
        float x4 = __half2float(x[((p4 & 0x3FFFFu) << 6) + lane]);
        float x5 = __half2float(x[((p5 & 0x3FFFFu) << 6) + lane]);
        float x6 = __half2float(x[((p6 & 0x3FFFFu) << 6) + lane]);
        float x7 = __half2float(x[((p7 & 0x3FFFFu) << 6) + lane]);
        acc = fmaf((float)(p0 >> 18), x0, acc);
        acc = fmaf((float)(p1 >> 18), x1, acc);
        acc = fmaf((float)(p2 >> 18), x2, acc);
        acc = fmaf((float)(p3 >> 18), x3, acc);
        acc = fmaf((float)(p4 >> 18), x4, acc);
        acc = fmaf((float)(p5 >> 18), x5, acc);
        acc = fmaf((float)(p6 >> 18), x6, acc);
        acc = fmaf((float)(p7 >> 18), x7, acc);
    }
    for (; e < s1; ++e) {
        unsigned p = pk[e];
        acc = fmaf((float)(p >> 18), __half2float(x[((p & 0x3FFFFu) << 6) + lane]), acc);
    }
    return acc * VAL_INV;
}

// remainder helper for the dual-row tail pull: 8-deep + scalar
__device__ __forceinline__ float pull_range(const unsigned* __restrict__ pk,
                                            const __half* __restrict__ x,
                                            int e, int s1, int lane, float acc) {
    for (; e + 8 <= s1; e += 8) {
        unsigned p0 = pk[e + 0], p1 = pk[e + 1], p2 = pk[e + 2], p3 = pk[e + 3];
        unsigned p4 = pk[e + 4], p5 = pk[e + 5], p6 = pk[e + 6], p7 = pk[e + 7];
        float x0 = __half2float(x[((p0 & 0x3FFFFu) << 6) + lane]);
        float x1 = __half2float(x[((p1 & 0x3FFFFu) << 6) + lane]);
        float x2 = __half2float(x[((p2 & 0x3FFFFu) << 6) + lane]);
        float x3 = __half2float(x[((p3 & 0x3FFFFu) << 6) + lane]);
        float x4 = __half2float(x[((p4 & 0x3FFFFu) << 6) + lane]);
        float x5 = __half2float(x[((p5 & 0x3FFFFu) << 6) + lane]);
        float x6 = __half2float(x[((p6 & 0x3FFFFu) << 6) + lane]);
        float x7 = __half2float(x[((p7 & 0x3FFFFu) << 6) + lane]);
        acc = fmaf((float)(p0 >> 18), x0, acc);
        acc = fmaf((float)(p1 >> 18), x1, acc);
        acc = fmaf((float)(p2 >> 18), x2, acc);
        acc = fmaf((float)(p3 >> 18), x3, acc);
        acc = fmaf((float)(p4 >> 18), x4, acc);
        acc = fmaf((float)(p5 >> 18), x5, acc);
        acc = fmaf((float)(p6 >> 18), x6, acc);
        acc = fmaf((float)(p7 >> 18), x7, acc);
    }
    for (; e < s1; ++e) {
        unsigned p = pk[e];
        acc = fmaf((float)(p >> 18), __half2float(x[((p & 0x3FFFFu) << 6) + lane]), acc);
    }
    return acc;
}

// ---------------------------------------------------------------------------
// pull SpMM: 4 rows (waves) per block
__global__ __launch_bounds__(256) void pull_kernel(const int* __restrict__ rowbeg,
                                                   const int* __restrict__ rowend,
                                                   const unsigned* __restrict__ pk,
                                                   const __half* __restrict__ x,
                                                   __half* __restrict__ y) {
    int lane = threadIdx.x & 63;
    int wv   = __builtin_amdgcn_readfirstlane(threadIdx.x >> 6);   // uniform
    int row  = blockIdx.x * 4 + wv;                                 // uniform
    if (row >= N_NODES) return;
    float acc = row_pull(rowbeg, rowend, pk, x, row, lane);
    y[((size_t)row << 6) + lane] = __float2half_rn(acc);
}

// ---------------------------------------------------------------------------
// mega-fused tail: one wave per batch element. Dual-interleaved layer-3 pulls
// for the user row AND item row (2x memory-level parallelism), combines
// l0(fp32 emb) + l1(nxt) + l2(cur) + l3 in registers, then softmax/sigmoid
// mix and writes gamma.
__global__ __launch_bounds__(256) void tail_kernel(const int* __restrict__ rowbeg,
                                                   const int* __restrict__ rowend,
                                                   const unsigned* __restrict__ pk,
                                                   const __half* __restrict__ cur,   // l2
                                                   const __half* __restrict__ nxt,   // l1
                                                   const float* __restrict__ eu,
                                                   const float* __restrict__ ei,
                                                   const float* __restrict__ exu,
                                                   const float* __restrict__ exi1,
                                                   const float* __restrict__ exi0,
                                                   const float* __restrict__ w_user,
                                                   const float* __restrict__ w_item,
                                                   const int* __restrict__ users,
                                                   const int* __restrict__ items,
                                                   const int* __restrict__ xijf,
                                                   float* __restrict__ out, int batch) {
    int lane = threadIdx.x & 63;
    int wv   = blockIdx.x * 4 + __builtin_amdgcn_readfirstlane(threadIdx.x >> 6);
    if (wv >= batch) return;
    int u    = users[wv];
    int it   = items[wv];
    int xf   = xijf[wv];
    int rowU = u;
    int rowI = NUM_USERS + it;

    // dual-interleaved layer-3 pulls from cur (l2): 16 gathers in flight
    int eA = rowbeg[rowU], sA = rowend[rowU];
    int eB = rowbeg[rowI], sB = rowend[rowI];
    float aU = 0.f, aI = 0.f;
    for (; eA + 8 <= sA && eB + 8 <= sB; eA += 8, eB += 8) {
        unsigned a0 = pk[eA + 0], a1 = pk[eA + 1], a2 = pk[eA + 2], a3 = pk[eA + 3];
        unsigned a4 = pk[eA + 4], a5 = pk[eA + 5], a6 = pk[eA + 6], a7 = pk[eA + 7];
        unsigned b0 = pk[eB + 0], b1 = pk[eB + 1], b2 = pk[eB + 2], b3 = pk[eB + 3];
        unsigned b4 = pk[eB + 4], b5 = pk[eB + 5], b6 = pk[eB + 6], b7 = pk[eB + 7];
        float xa0 = __half2float(cur[((a0 & 0x3FFFFu) << 6) + lane]);
        float xa1 = __half2float(cur[((a1 & 0x3FFFFu) << 6) + lane]);
        float xa2 = __half2float(cur[((a2 & 0x3FFFFu) << 6) + lane]);
        float xa3 = __half2float(cur[((a3 & 0x3FFFFu) << 6) + lane]);
        float xa4 = __half2float(cur[((a4 & 0x3FFFFu) << 6) + lane]);
        float xa5 = __half2float(cur[((a5 & 0x3FFFFu) << 6) + lane]);
        float xa6 = __half2float(cur[((a6 & 0x3FFFFu) << 6) + lane]);
        float xa7 = __half2float(cur[((a7 & 0x3FFFFu) << 6) + lane]);
        float xb0 = __half2float(cur[((b0 & 0x3FFFFu) << 6) + lane]);
        float xb1 = __half2float(cur[((b1 & 0x3FFFFu) << 6) + lane]);
        float xb2 = __half2float(cur[((b2 & 0x3FFFFu) << 6) + lane]);
        float xb3 = __half2float(cur[((b3 & 0x3FFFFu) << 6) + lane]);
        float xb4 = __half2float(cur[((b4 & 0x3FFFFu) << 6) + lane]);
        float xb5 = __half2float(cur[((b5 & 0x3FFFFu) << 6) + lane]);
        float xb6 = __half2float(cur[((b6 & 0x3FFFFu) << 6) + lane]);
        float xb7 = __half2float(cur[((b7 & 0x3FFFFu) << 6) + lane]);
        aU = fmaf((float)(a0 >> 18), xa0, aU);
        aU = fmaf((float)(a1 >> 18), xa1, aU);
        aU = fmaf((float)(a2 >> 18), xa2, aU);
        aU = fmaf((float)(a3 >> 18), xa3, aU);
        aU = fmaf((float)(a4 >> 18), xa4, aU);
        aU = fmaf((float)(a5 >> 18), xa5, aU);
        aU = fmaf((float)(a6 >> 18), xa6, aU);
        aU = fmaf((float)(a7 >> 18), xa7, aU);
        aI = fmaf((float)(b0 >> 18), xb0, aI);
        aI = fmaf((float)(b1 >> 18), xb1, aI);
        aI = fmaf((float)(b2 >> 18), xb2, aI);
        aI = fmaf((float)(b3 >> 18), xb3, aI);
        aI = fmaf((float)(b4 >> 18), xb4, aI);
        aI = fmaf((float)(b5 >> 18), xb5, aI);
        aI = fmaf((float)(b6 >> 18), xb6, aI);
        aI = fmaf((float)(b7 >> 18), xb7, aI);
    }
    aU = pull_range(pk, cur, eA, sA, lane, aU);
    aI = pull_range(pk, cur, eB, sB, lane, aI);
    float l3u = aU * VAL_INV;
    float l3i = aI * VAL_INV;

    float wu = w_user[0] * 0.25f;
    float wi = w_item[0] * 0.25f;

    float su = eu[((size_t)u  << 6) + lane]
             + __half2float(nxt[((size_t)rowU << 6) + lane])
             + __half2float(cur[((size_t)rowU << 6) + lane])
             + l3u;
    float si = ei[((size_t)it << 6) + lane]
             + __half2float(nxt[((size_t)rowI << 6) + lane])
             + __half2float(cur[((size_t)rowI << 6) + lane])
             + l3i;
    float ua = wu * su;
    float ia = wi * si;

    float ub = -INFINITY, ib = 0.f;
    if (lane < 16) {
        ub = exu[(size_t)u * 16 + lane];
        ib = xf ? exi1[(size_t)it * 16 + lane] : exi0[(size_t)it * 16 + lane];
    }

    float m = fmaxf(ua, ub);
    #pragma unroll
    for (int off = 32; off; off >>= 1) m = fmaxf(m, __shfl_xor(m, off));
    float ea = expf(ua - m);
    float eb = (lane < 16) ? expf(ub - m) : 0.f;
    float s = ea + eb;
    #pragma unroll
    for (int off = 32; off; off >>= 1) s += __shfl_xor(s, off);
    float inv = 1.f / s;

    float sa = 1.f / (1.f + expf(-ia));
    float sb = (lane < 16) ? 1.f / (1.f + expf(-ib)) : 0.f;

    float g = ea * inv * sa + eb * inv * sb;
    #pragma unroll
    for (int off = 32; off; off >>= 1) g += __shfl_xor(g, off);
    if (lane == 0) out[wv] = g;
}

// ---------------------------------------------------------------------------
extern "C" void kernel_launch(void* const* d_in, const int* in_sizes, int n_in,
                              void* d_out, int out_size, void* d_ws, size_t ws_size,
                              hipStream_t stream) {
    const float* emb_user = (const float*)d_in[0];
    const float* emb_item = (const float*)d_in[1];
    const float* exu      = (const float*)d_in[2];
    const float* exi1     = (const float*)d_in[3];
    const float* exi0     = (const float*)d_in[4];
    const float* w_user   = (const float*)d_in[5];
    const float* w_item   = (const float*)d_in[6];
    const float* gvals    = (const float*)d_in[7];
    const int*   grows    = (const int*)d_in[8];
    const int*   gcols    = (const int*)d_in[9];
    const int*   users    = (const int*)d_in[10];
    const int*   items    = (const int*)d_in[11];
    const int*   xijf     = (const int*)d_in[12];
    float*       out      = (float*)d_out;

    const int nnz   = in_sizes[7];
    const int batch = in_sizes[10];

    const size_t node_elems  = (size_t)N_NODES * DIM;           // 9.6M
    const size_t STAGE_SLOTS = (size_t)NBS * SLOTS;             // 9.6M slots
    char* w = (char*)d_ws;
    unsigned*       axbuf  = (unsigned*)w;                      // 38.4 MB (staging)
    __half*         cur    = (__half*)w;                        // aliases axbuf (19.2 MB)
    __half*         nxt    = cur + node_elems;                  // aliases axbuf (19.2 MB)
    w += STAGE_SLOTS * 4;
    unsigned short* rowbuf = (unsigned short*)w;  w += STAGE_SLOTS * 2;             // 19.2 MB
    unsigned*       pk     = (unsigned*)w;        w += (size_t)NBS * PKSLOTS * 4;   // 26.7 MB
    int*            rowbeg = (int*)w;             w += (size_t)N_NODES * 4;         // 0.6 MB
    int*            rowend = (int*)w;             w += (size_t)N_NODES * 4;         // 0.6 MB
    int*            gcur   = (int*)w;             w += (size_t)NBS * GPAD * 4;
    // total ~85.5 MB (< 115.2 MB proven in round 0)

    const int tb = 256;
    const int total4 = N_NODES * (DIM / 4);

    // ---- CSR build (staging live) ----
    gcur_init_kernel<<<(NBS + tb - 1) / tb, tb, 0, stream>>>(gcur);
    binned_scatter_kernel<<<SCAT_WGS, 256, 0, stream>>>(grows, gcols, gvals, gcur,
                                                        axbuf, rowbuf, nnz);
    bucket_build_kernel<<<NBS, BBT, 0, stream>>>(gcur, axbuf, rowbuf, pk, rowbeg, rowend);

    // ---- dense init (staging dead; cur/nxt take over axbuf's space) ----
    copy_init_kernel<<<(total4 + tb - 1) / tb, tb, 0, stream>>>(
        (const float4*)emb_user, (const float4*)emb_item, (ushort4*)cur, total4);

    const int pull_blocks = (N_NODES + 3) / 4;       // 4 rows (waves) per block
    const int tail_blocks = (batch + 3) / 4;

    pull_kernel<<<pull_blocks, tb, 0, stream>>>(rowbeg, rowend, pk, cur, nxt);   // l1 = A*l0
    pull_kernel<<<pull_blocks, tb, 0, stream>>>(rowbeg, rowend, pk, nxt, cur);   // l2 = A*l1
    tail_kernel<<<tail_blocks, tb, 0, stream>>>(
        rowbeg, rowend, pk, cur, nxt, emb_user, emb_item,
        exu, exi1, exi0, w_user, w_item, users, items, xijf, out, batch);
}